// Round 9
// baseline (89.849 us; speedup 1.0000x reference)
//
#include <hip/hip_runtime.h>

#define DIMc 512
#define Sc   4096
#define Bc   4
#define Mc   (Bc*Sc)     // 16384
#define N1c  (3*DIMc)    // 1536
#define Kc   DIMc        // 512
#define HDc  64
#define HALFW 32

using short8  = __attribute__((ext_vector_type(8))) short;
using ushort4v= __attribute__((ext_vector_type(4))) unsigned short;
using f32x4   = __attribute__((ext_vector_type(4))) float;

__device__ __forceinline__ unsigned short f2b(float f) {
  unsigned int u = __builtin_bit_cast(unsigned int, f);
  u += 0x7FFFu + ((u >> 16) & 1u);
  return (unsigned short)(u >> 16);
}

// global -> LDS, 16B per lane. lds base must be wave-uniform (HW adds lane*16).
__device__ __forceinline__ void gll16(const unsigned short* g, char* lds_uniform) {
  __builtin_amdgcn_global_load_lds(
      (const __attribute__((address_space(1))) unsigned int*)g,
      (__attribute__((address_space(3))) unsigned int*)lds_uniform,
      16, 0, 0);
}

// ---------------- merged weight convert: W [K][N] fp32 -> wT [N][K] bf16, swizzled ----------------
__global__ void k_convert_w2(const float* __restrict__ W1, unsigned short* __restrict__ wT1,
                             const float* __restrict__ W2, unsigned short* __restrict__ wT2) {
  int b = blockIdx.x;
  const float* W; unsigned short* wT; int Nn, t;
  if (b < 384) { W = W1; wT = wT1; Nn = N1c;  t = b * 256 + threadIdx.x; }
  else         { W = W2; wT = wT2; Nn = DIMc; t = (b - 384) * 256 + threadIdx.x; }
  int s = t / Nn;                             // k-slot 0..63
  int n = t - s * Nn;
  short8 v;
#pragma unroll
  for (int j = 0; j < 8; ++j) v[j] = (short)f2b(W[(size_t)(s * 8 + j) * Nn + n]);
  int sp = (s & ~7) | ((s & 7) ^ (n & 7));
  *(short8*)(wT + (size_t)n * Kc + sp * 8) = v;
}

// ---------------- 128-tile 2-phase mainloop (for proj; B/A both bf16 via gll16) ----------------
__device__ __forceinline__ void gemm_main2(const unsigned short* __restrict__ A,
                                           const unsigned short* __restrict__ Bt,
                                           int m0, int n0, int lane, int w,
                                           char* smem, f32x4 acc[4][4]) {
  int g = lane >> 4;
  int mbase = (w & 1) * 64;
  int nbase = (w >> 1) * 64;
  const int NKT = Kc / 64;   // 8

  auto STAGE = [&](int buf, int kt) {
    char* base = smem + (buf << 15);
#pragma unroll
    for (int i = 0; i < 4; ++i) {
      int cbase = i * 256 + w * 64;
      int c = cbase + lane;
      int row = c >> 3, sl = c & 7;
      gll16(A + (size_t)(m0 + row) * Kc + kt * 64 + sl * 8, base + cbase * 16);
    }
#pragma unroll
    for (int i = 0; i < 4; ++i) {
      int cbase = i * 256 + w * 64;
      int c = cbase + lane;
      int row = c >> 3, sl = c & 7;
      gll16(Bt + (size_t)(n0 + row) * Kc + kt * 64 + sl * 8, base + 16384 + cbase * 16);
    }
  };

  STAGE(0, 0);
  int cur = 0;
  for (int kt = 0; kt < NKT; ++kt) {
    if (kt + 1 < NKT) {
      STAGE(cur ^ 1, kt + 1);
      asm volatile("s_waitcnt vmcnt(8)" ::: "memory");
    } else {
      asm volatile("s_waitcnt vmcnt(0)" ::: "memory");
    }
    __builtin_amdgcn_s_barrier();
    __builtin_amdgcn_sched_barrier(0);
    unsigned short* As = (unsigned short*)(smem + (cur << 15));
    unsigned short* Bs = (unsigned short*)(smem + (cur << 15) + 16384);
#pragma unroll
    for (int ksub = 0; ksub < 2; ++ksub) {
      short8 af[4], bf[4];
#pragma unroll
      for (int mt = 0; mt < 4; ++mt) {
        int row = mbase + mt * 16 + (lane & 15);
        int slot = ((ksub << 2) + g) ^ (row & 7);
        af[mt] = *(const short8*)(As + row * 64 + slot * 8);
      }
#pragma unroll
      for (int ct = 0; ct < 4; ++ct) {
        int row = nbase + ct * 16 + (lane & 15);
        int slot = ((ksub << 2) + g) ^ (row & 7);
        bf[ct] = *(const short8*)(Bs + row * 64 + slot * 8);
      }
#pragma unroll
      for (int mt = 0; mt < 4; ++mt)
#pragma unroll
        for (int ct = 0; ct < 4; ++ct)
          acc[mt][ct] = __builtin_amdgcn_mfma_f32_16x16x32_bf16(af[mt], bf[ct], acc[mt][ct], 0, 0, 0);
    }
    __builtin_amdgcn_sched_barrier(0);
    __builtin_amdgcn_s_barrier();
    cur ^= 1;
  }
}

// ---------------- GEMM1: qkv = x @ W_qkv + b, A converted fp32->bf16 in-kernel ----------------
// 128x128 tile, BK=64, 4 waves. A: reg-staged from fp32 x (f2b + swizzled ds_write);
// B: gll16 from pre-swizzled wT. 1 barrier/kt; vmcnt(0)+WRITE_A after compute (T14 split).
__global__ __launch_bounds__(256, 2) void k_gemm_qkv(
    const float* __restrict__ x, const unsigned short* __restrict__ wT,
    const float* __restrict__ bias, unsigned short* __restrict__ qb,
    unsigned short* __restrict__ kb, unsigned short* __restrict__ vb) {
  __shared__ __align__(16) char smem[65536];
  // L2-locality remap: XCD x owns bm in [16x,16x+16); all 12 bn per bm before advancing.
  int bid = blockIdx.x;                        // 1536 = 8 XCD * 16 bm * 12 bn
  int xcd = bid & 7, ii = bid >> 3;            // ii in [0,192)
  int bm = xcd * 16 + ii / 12;
  int bn = ii - (ii / 12) * 12;
  int m0 = bm * 128, n0 = bn * 128;
  int tid = threadIdx.x;
  int lane = tid & 63, w = tid >> 6, g = lane >> 4, nl = lane & 15;

  f32x4 acc[4][4];
#pragma unroll
  for (int i2 = 0; i2 < 4; ++i2)
#pragma unroll
    for (int j = 0; j < 4; ++j) acc[i2][j] = f32x4{0.f, 0.f, 0.f, 0.f};

  float4 fa[4][2];
  auto LOAD_A = [&](int kt) {
#pragma unroll
    for (int i = 0; i < 4; ++i) {
      int gid = i * 256 + tid;
      int row = gid >> 3, sl = gid & 7;
      const float* src = x + (size_t)(m0 + row) * DIMc + kt * 64 + sl * 8;
      fa[i][0] = *(const float4*)src;
      fa[i][1] = *(const float4*)(src + 4);
    }
  };
  auto WRITE_A = [&](int buf) {
    unsigned short* As = (unsigned short*)(smem + (buf << 15));
#pragma unroll
    for (int i = 0; i < 4; ++i) {
      int gid = i * 256 + tid;
      int row = gid >> 3, sl = gid & 7;
      short8 v;
      v[0]=(short)f2b(fa[i][0].x); v[1]=(short)f2b(fa[i][0].y);
      v[2]=(short)f2b(fa[i][0].z); v[3]=(short)f2b(fa[i][0].w);
      v[4]=(short)f2b(fa[i][1].x); v[5]=(short)f2b(fa[i][1].y);
      v[6]=(short)f2b(fa[i][1].z); v[7]=(short)f2b(fa[i][1].w);
      *(short8*)(As + row * 64 + (sl ^ (row & 7)) * 8) = v;
    }
  };
  auto STAGE_B = [&](int buf, int kt) {
    char* base = smem + (buf << 15) + 16384;
#pragma unroll
    for (int i = 0; i < 4; ++i) {
      int cbase = i * 256 + w * 64;
      int c = cbase + lane;
      int row = c >> 3, sl = c & 7;
      gll16(wT + (size_t)(n0 + row) * Kc + kt * 64 + sl * 8, base + cbase * 16);
    }
  };

  // prologue: stage tile 0
  LOAD_A(0);
  STAGE_B(0, 0);
  asm volatile("s_waitcnt vmcnt(0)" ::: "memory");
  WRITE_A(0);
  __syncthreads();

  int mbase = (w & 1) * 64, nbase = (w >> 1) * 64;
  for (int kt = 0; kt < 8; ++kt) {
    int cur = kt & 1;
    if (kt + 1 < 8) { LOAD_A(kt + 1); STAGE_B(cur ^ 1, kt + 1); }
    unsigned short* As = (unsigned short*)(smem + (cur << 15));
    unsigned short* Bs = (unsigned short*)(smem + (cur << 15) + 16384);
#pragma unroll
    for (int ksub = 0; ksub < 2; ++ksub) {
      short8 af[4], bf[4];
#pragma unroll
      for (int mt = 0; mt < 4; ++mt) {
        int row = mbase + mt * 16 + nl;
        int slot = ((ksub << 2) + g) ^ (row & 7);
        af[mt] = *(const short8*)(As + row * 64 + slot * 8);
      }
#pragma unroll
      for (int ct = 0; ct < 4; ++ct) {
        int row = nbase + ct * 16 + nl;
        int slot = ((ksub << 2) + g) ^ (row & 7);
        bf[ct] = *(const short8*)(Bs + row * 64 + slot * 8);
      }
#pragma unroll
      for (int mt = 0; mt < 4; ++mt)
#pragma unroll
        for (int ct = 0; ct < 4; ++ct)
          acc[mt][ct] = __builtin_amdgcn_mfma_f32_16x16x32_bf16(af[mt], bf[ct], acc[mt][ct], 0, 0, 0);
    }
    if (kt + 1 < 8) {
      asm volatile("s_waitcnt vmcnt(0)" ::: "memory");  // A regs + B gll16 landed
      WRITE_A(cur ^ 1);
    }
    __syncthreads();
  }

  // ---- epilogue: restage C tile (bf16, bias added) into LDS, then full-line stores ----
  unsigned short* Ct = (unsigned short*)smem;  // 128x128 bf16 = 32 KB
  float bsv[4];
#pragma unroll
  for (int ct = 0; ct < 4; ++ct) bsv[ct] = bias[n0 + (w >> 1) * 64 + ct * 16 + nl];
  bool isV = (n0 >= 1024);
  if (!isV) {
#pragma unroll
    for (int mt = 0; mt < 4; ++mt)
#pragma unroll
      for (int ct = 0; ct < 4; ++ct)
#pragma unroll
        for (int r = 0; r < 4; ++r) {
          int m = (w & 1) * 64 + mt * 16 + 4 * g + r;
          int n = (w >> 1) * 64 + ct * 16 + nl;
          Ct[m * 128 + (n ^ (g << 4))] = f2b(acc[mt][ct][r] + bsv[ct]);
        }
  } else {
#pragma unroll
    for (int mt = 0; mt < 4; ++mt)
#pragma unroll
      for (int ct = 0; ct < 4; ++ct) {
        int n = (w >> 1) * 64 + ct * 16 + nl;
        int mchunk = (w & 1) * 16 + mt * 4 + g;
        ushort4v pk;
#pragma unroll
        for (int r = 0; r < 4; ++r) pk[r] = f2b(acc[mt][ct][r] + bsv[ct]);
        *(ushort4v*)(Ct + n * 128 + ((mchunk ^ (n & 15)) << 2)) = pk;
      }
  }
  __syncthreads();
  if (!isV) {
    unsigned short* dst0 = (n0 >= 512) ? kb : qb;
#pragma unroll
    for (int i2 = 0; i2 < 8; ++i2) {
      int cid = i2 * 256 + tid;
      int row = cid >> 4, c = cid & 15;
      int gg = (row >> 2) & 3;
      short8 vv = *(const short8*)(Ct + row * 128 + ((c ^ (gg << 1)) << 3));
      int m = m0 + row, b = m >> 12, s = m & 4095;
      int ng = n0 + c * 8, h = (ng >> 6) & 7, d0 = ng & 63;
      *(short8*)(dst0 + ((size_t)(b * 8 + h) * Sc + s) * HDc + d0) = vv;
    }
  } else {
#pragma unroll
    for (int i2 = 0; i2 < 8; ++i2) {
      int cid = i2 * 256 + tid;
      int n = cid & 127, m8i = cid >> 7;
      int cpair = (m8i * 2) ^ (n & 14);
      short8 vv = *(const short8*)(Ct + n * 128 + (cpair << 2));
      if (n & 1) vv = __builtin_shufflevector(vv, vv, 4, 5, 6, 7, 0, 1, 2, 3);
      int ng = n0 + n, h = (ng >> 6) & 7, d = ng & 63;
      int m = m0 + m8i * 8, b = m >> 12, s = m & 4095;
      *(short8*)(vb + ((size_t)(b * 8 + h) * HDc + d) * Sc + s) = vv;  // V^T
    }
  }
}

// ---------------- banded attention (unchanged from round 7) ----------------
__global__ void k_attn(const unsigned short* __restrict__ qb,
                       const unsigned short* __restrict__ kb,
                       const unsigned short* __restrict__ vb,
                       unsigned short* __restrict__ attnb) {
  __shared__ __align__(16) char smem[40960];
  unsigned short* Qt = (unsigned short*)smem;
  unsigned short* Kt = (unsigned short*)(smem + 8192);
  unsigned short* Vt = (unsigned short*)(smem + 24576);
  unsigned short* Pt = (unsigned short*)smem;
  int bid = blockIdx.x;                        // 2048 = 8 * 4 * 64
  int x = bid & 7, i = bid >> 3;
  int bh = x * 4 + (i >> 6), qt = i & 63;
  int q0 = qt * 64;
  int tid = threadIdx.x;
  int lane = tid & 63, w = tid >> 6, g = lane >> 4;

  const unsigned short* qsrc = qb + ((long)bh * Sc + q0) * HDc;
#pragma unroll
  for (int i2 = 0; i2 < 2; ++i2) {
    int wc = i2 * 4 + w;
    int cid = wc * 64 + lane, row = cid >> 3, sl = cid & 7;
    gll16(qsrc + row * 64 + (sl ^ (row & 7)) * 8, (char*)Qt + wc * 1024);
  }
  const unsigned short* ksrc = kb + ((long)bh * Sc + q0 - HALFW) * HDc;
#pragma unroll
  for (int i2 = 0; i2 < 4; ++i2) {
    int wc = i2 * 4 + w;
    int cid = wc * 64 + lane, row = cid >> 3, sl = cid & 7;
    gll16(ksrc + row * 64 + (sl ^ (row & 7)) * 8, (char*)Kt + wc * 1024);
  }
  const unsigned short* vsrc = vb + (long)bh * HDc * Sc + (q0 - HALFW);
#pragma unroll
  for (int i2 = 0; i2 < 4; ++i2) {
    int wc = i2 * 4 + w;
    int cid = wc * 64 + lane, row = cid >> 4, sl = cid & 15;
    gll16(vsrc + (long)row * Sc + (sl ^ (row & 15)) * 8, (char*)Vt + wc * 1024);
  }
  __syncthreads();

  f32x4 sc[8];
#pragma unroll
  for (int ct = 0; ct < 8; ++ct) sc[ct] = f32x4{0.f, 0.f, 0.f, 0.f};
#pragma unroll
  for (int ksub = 0; ksub < 2; ++ksub) {
    int arow = w * 16 + (lane & 15);
    int aslot = ((ksub << 2) + g) ^ (arow & 7);
    short8 af = *(const short8*)(Qt + arow * 64 + aslot * 8);
#pragma unroll
    for (int ct = 0; ct < 8; ++ct) {
      int brow = ct * 16 + (lane & 15);
      int bslot = ((ksub << 2) + g) ^ (brow & 7);
      short8 bf = *(const short8*)(Kt + brow * 64 + bslot * 8);
      sc[ct] = __builtin_amdgcn_mfma_f32_16x16x32_bf16(af, bf, sc[ct], 0, 0, 0);
    }
  }
  float rsum[4] = {0.f, 0.f, 0.f, 0.f};
#pragma unroll
  for (int ct = 0; ct < 8; ++ct) {
    int keyl = ct * 16 + (lane & 15);
    int keyg = q0 - HALFW + keyl;
#pragma unroll
    for (int r = 0; r < 4; ++r) {
      int q = q0 + w * 16 + 4 * g + r;
      int dlt = keyg - q;
      bool valid = (dlt >= -HALFW) && (dlt <= HALFW) && (keyg >= 0) && (keyg < Sc);
      float pv = valid ? __expf(sc[ct][r] * 0.125f) : 0.f;
      sc[ct][r] = pv;
      rsum[r] += pv;
    }
  }
#pragma unroll
  for (int r = 0; r < 4; ++r) {
    float v = rsum[r];
    v += __shfl_xor(v, 1); v += __shfl_xor(v, 2); v += __shfl_xor(v, 4); v += __shfl_xor(v, 8);
    rsum[r] = 1.0f / v;
  }
  __syncthreads();
#pragma unroll
  for (int ct = 0; ct < 8; ++ct) {
    int keyl = ct * 16 + (lane & 15);
#pragma unroll
    for (int r = 0; r < 4; ++r) {
      int prow = w * 16 + 4 * g + r;
      int sp = (keyl >> 3) ^ (prow & 15);
      Pt[prow * 128 + sp * 8 + (keyl & 7)] = f2b(sc[ct][r]);
    }
  }
  __syncthreads();
  f32x4 o[4];
#pragma unroll
  for (int i2 = 0; i2 < 4; ++i2) o[i2] = f32x4{0.f, 0.f, 0.f, 0.f};
#pragma unroll
  for (int ks = 0; ks < 4; ++ks) {
    int arow = w * 16 + (lane & 15);
    int aslot = ((ks << 2) + g) ^ (arow & 15);
    short8 af = *(const short8*)(Pt + arow * 128 + aslot * 8);
#pragma unroll
    for (int ct2 = 0; ct2 < 4; ++ct2) {
      int vrow = ct2 * 16 + (lane & 15);
      int vslot = ((ks << 2) + g) ^ (vrow & 15);
      short8 bf = *(const short8*)(Vt + vrow * 128 + vslot * 8);
      o[ct2] = __builtin_amdgcn_mfma_f32_16x16x32_bf16(af, bf, o[ct2], 0, 0, 0);
    }
  }
  int h = bh & 7, b = bh >> 3;
#pragma unroll
  for (int ct2 = 0; ct2 < 4; ++ct2) {
    int d = ct2 * 16 + (lane & 15);
    int col = h * 64 + d;
    int slot = col >> 3;
#pragma unroll
    for (int r = 0; r < 4; ++r) {
      int q = q0 + w * 16 + 4 * g + r;
      int sp = (slot & ~7) | ((slot & 7) ^ (q & 7));
      attnb[((size_t)b * Sc + q) * DIMc + sp * 8 + (col & 7)] = f2b(o[ct2][r] * rsum[r]);
    }
  }
}

// ---------------- GEMM2: out = attn @ W_proj + b (unchanged 128-tile 2-phase) ----------------
__global__ void k_gemm_proj(const unsigned short* __restrict__ ab,
                            const unsigned short* __restrict__ wT,
                            const float* __restrict__ bias,
                            float* __restrict__ out) {
  __shared__ __align__(16) char smem[65536];
  int bid = blockIdx.x;                        // 512 = 8 XCD * 16 bm * 4 bn
  int x = bid & 7, i = bid >> 3;
  int bm = x * 16 + (i >> 2), bn = i & 3;
  int m0 = bm * 128, n0 = bn * 128;
  int lane = threadIdx.x & 63, w = threadIdx.x >> 6, g = lane >> 4;
  f32x4 acc[4][4];
#pragma unroll
  for (int i2 = 0; i2 < 4; ++i2)
#pragma unroll
    for (int j = 0; j < 4; ++j) acc[i2][j] = f32x4{0.f, 0.f, 0.f, 0.f};
  gemm_main2(ab, wT, m0, n0, lane, w, smem, acc);
#pragma unroll
  for (int ct = 0; ct < 4; ++ct) {
    int n = n0 + (w >> 1) * 64 + ct * 16 + (lane & 15);
    float bs = bias[n];
#pragma unroll
    for (int mt = 0; mt < 4; ++mt) {
#pragma unroll
      for (int r = 0; r < 4; ++r) {
        int m = m0 + (w & 1) * 64 + mt * 16 + 4 * g + r;
        out[(size_t)m * DIMc + n] = acc[mt][ct][r] + bs;
      }
    }
  }
}

extern "C" void kernel_launch(void* const* d_in, const int* in_sizes, int n_in,
                              void* d_out, int out_size, void* d_ws, size_t ws_size,
                              hipStream_t stream) {
  const float* x     = (const float*)d_in[0];
  const float* Wqkv  = (const float*)d_in[1];
  const float* bqkv  = (const float*)d_in[2];
  const float* Wproj = (const float*)d_in[3];
  const float* bproj = (const float*)d_in[4];
  float* out = (float*)d_out;

  char* ws = (char*)d_ws;
  const size_t SZ_QKV = (size_t)32 * Sc * HDc * 2;   // 16,777,216 each
  const size_t SZ_ATT = (size_t)Mc * DIMc * 2;       // 16,777,216
  size_t off = 0;
  unsigned short* qb    = (unsigned short*)(ws + off); off += SZ_QKV;
  unsigned short* kb    = (unsigned short*)(ws + off); off += SZ_QKV;
  unsigned short* vb    = (unsigned short*)(ws + off); off += SZ_QKV;
  unsigned short* attnb = (unsigned short*)(ws + off); off += SZ_ATT;
  unsigned short* wqkvT = (unsigned short*)(ws + off); off += (size_t)N1c * Kc * 2;
  unsigned short* wprjT = (unsigned short*)(ws + off); off += (size_t)DIMc * Kc * 2;
  if (ws_size < off) return;  // insufficient scratch; fail visibly

  k_convert_w2<<<dim3(512),  dim3(256), 0, stream>>>(Wqkv, wqkvT, Wproj, wprjT);
  k_gemm_qkv  <<<dim3(1536), dim3(256), 0, stream>>>(x, wqkvT, bqkv, qb, kb, vb);
  k_attn      <<<dim3(2048), dim3(256), 0, stream>>>(qb, kb, vb, attnb);
  k_gemm_proj <<<dim3(512),  dim3(256), 0, stream>>>(attnb, wprjT, bproj, out);
}

// Round 10
// 79.897 us; speedup vs baseline: 1.1246x; 1.1246x over previous
//
#include <hip/hip_runtime.h>

#define DIMc 512
#define Sc   4096
#define Bc   4
#define Mc   (Bc*Sc)     // 16384
#define N1c  (3*DIMc)    // 1536
#define Kc   DIMc        // 512
#define HDc  64
#define HALFW 32

using short8  = __attribute__((ext_vector_type(8))) short;
using ushort4v= __attribute__((ext_vector_type(4))) unsigned short;
using f32x4   = __attribute__((ext_vector_type(4))) float;

__device__ __forceinline__ unsigned short f2b(float f) {
  unsigned int u = __builtin_bit_cast(unsigned int, f);
  u += 0x7FFFu + ((u >> 16) & 1u);
  return (unsigned short)(u >> 16);
}

// global -> LDS, 16B per lane. lds base must be wave-uniform (HW adds lane*16).
__device__ __forceinline__ void gll16(const unsigned short* g, char* lds_uniform) {
  __builtin_amdgcn_global_load_lds(
      (const __attribute__((address_space(1))) unsigned int*)g,
      (__attribute__((address_space(3))) unsigned int*)lds_uniform,
      16, 0, 0);
}

// ---------------- merged convert: x -> xb (swizzled bf16), W -> wT (transposed, swizzled) ----------------
__global__ void k_convert_all(const float* __restrict__ x,  unsigned short* __restrict__ xb,
                              const float* __restrict__ W1, unsigned short* __restrict__ wT1,
                              const float* __restrict__ W2, unsigned short* __restrict__ wT2) {
  int bid = blockIdx.x;
  if (bid < 4096) {
    int t = bid * 256 + threadIdx.x;           // 16384*64 slots
    int row = t >> 6, s = t & 63;
    const float* src = x + (size_t)row * DIMc + s * 8;
    float4 a = *(const float4*)(src);
    float4 b = *(const float4*)(src + 4);
    int sp = (s & ~7) | ((s & 7) ^ (row & 7));
    short8 v;
    v[0]=(short)f2b(a.x); v[1]=(short)f2b(a.y); v[2]=(short)f2b(a.z); v[3]=(short)f2b(a.w);
    v[4]=(short)f2b(b.x); v[5]=(short)f2b(b.y); v[6]=(short)f2b(b.z); v[7]=(short)f2b(b.w);
    *(short8*)(xb + (size_t)row * DIMc + sp * 8) = v;
  } else {
    const float* W; unsigned short* wT; int Nn, t;
    if (bid < 4480) { W = W1; wT = wT1; Nn = N1c;  t = (bid - 4096) * 256 + threadIdx.x; }
    else            { W = W2; wT = wT2; Nn = DIMc; t = (bid - 4480) * 256 + threadIdx.x; }
    int s = t / Nn;                            // k-slot 0..63
    int n = t - s * Nn;
    short8 v;
#pragma unroll
    for (int j = 0; j < 8; ++j) v[j] = (short)f2b(W[(size_t)(s * 8 + j) * Nn + n]);
    int sp = (s & ~7) | ((s & 7) ^ (n & 7));
    *(short8*)(wT + (size_t)n * Kc + sp * 8) = v;
  }
}

// ---------------- 128-tile 2-phase mainloop (A and B both gll16, pre-swizzled) ----------------
__device__ __forceinline__ void gemm_main2(const unsigned short* __restrict__ A,
                                           const unsigned short* __restrict__ Bt,
                                           int m0, int n0, int lane, int w,
                                           char* smem, f32x4 acc[4][4]) {
  int g = lane >> 4;
  int mbase = (w & 1) * 64;
  int nbase = (w >> 1) * 64;
  const int NKT = Kc / 64;   // 8

  auto STAGE = [&](int buf, int kt) {
    char* base = smem + (buf << 15);
#pragma unroll
    for (int i = 0; i < 4; ++i) {
      int cbase = i * 256 + w * 64;
      int c = cbase + lane;
      int row = c >> 3, sl = c & 7;
      gll16(A + (size_t)(m0 + row) * Kc + kt * 64 + sl * 8, base + cbase * 16);
    }
#pragma unroll
    for (int i = 0; i < 4; ++i) {
      int cbase = i * 256 + w * 64;
      int c = cbase + lane;
      int row = c >> 3, sl = c & 7;
      gll16(Bt + (size_t)(n0 + row) * Kc + kt * 64 + sl * 8, base + 16384 + cbase * 16);
    }
  };

  STAGE(0, 0);
  int cur = 0;
  for (int kt = 0; kt < NKT; ++kt) {
    if (kt + 1 < NKT) {
      STAGE(cur ^ 1, kt + 1);
      asm volatile("s_waitcnt vmcnt(8)" ::: "memory");
    } else {
      asm volatile("s_waitcnt vmcnt(0)" ::: "memory");
    }
    __builtin_amdgcn_s_barrier();
    __builtin_amdgcn_sched_barrier(0);
    unsigned short* As = (unsigned short*)(smem + (cur << 15));
    unsigned short* Bs = (unsigned short*)(smem + (cur << 15) + 16384);
#pragma unroll
    for (int ksub = 0; ksub < 2; ++ksub) {
      short8 af[4], bf[4];
#pragma unroll
      for (int mt = 0; mt < 4; ++mt) {
        int row = mbase + mt * 16 + (lane & 15);
        int slot = ((ksub << 2) + g) ^ (row & 7);
        af[mt] = *(const short8*)(As + row * 64 + slot * 8);
      }
#pragma unroll
      for (int ct = 0; ct < 4; ++ct) {
        int row = nbase + ct * 16 + (lane & 15);
        int slot = ((ksub << 2) + g) ^ (row & 7);
        bf[ct] = *(const short8*)(Bs + row * 64 + slot * 8);
      }
#pragma unroll
      for (int mt = 0; mt < 4; ++mt)
#pragma unroll
        for (int ct = 0; ct < 4; ++ct)
          acc[mt][ct] = __builtin_amdgcn_mfma_f32_16x16x32_bf16(af[mt], bf[ct], acc[mt][ct], 0, 0, 0);
    }
    __builtin_amdgcn_sched_barrier(0);
    __builtin_amdgcn_s_barrier();
    cur ^= 1;
  }
}

// ---------------- GEMM1: qkv = x @ W_qkv + b (round-7 proven structure) ----------------
__global__ void k_gemm_qkv(const unsigned short* __restrict__ xb,
                           const unsigned short* __restrict__ wT,
                           const float* __restrict__ bias,
                           unsigned short* __restrict__ qb,
                           unsigned short* __restrict__ kb,
                           unsigned short* __restrict__ vb) {
  __shared__ __align__(16) char smem[65536];
  // L2-locality remap: XCD x owns bm in [16x,16x+16); all 12 bn per bm before advancing.
  int bid = blockIdx.x;                        // 1536 = 8 XCD * 16 bm * 12 bn
  int x = bid & 7, i = bid >> 3;               // i in [0,192)
  int bm = x * 16 + i / 12;
  int bn = i - (i / 12) * 12;
  int m0 = bm * 128, n0 = bn * 128;
  int lane = threadIdx.x & 63, w = threadIdx.x >> 6, g = lane >> 4, nl = lane & 15;
  f32x4 acc[4][4];
#pragma unroll
  for (int i2 = 0; i2 < 4; ++i2)
#pragma unroll
    for (int j = 0; j < 4; ++j) acc[i2][j] = f32x4{0.f, 0.f, 0.f, 0.f};
  gemm_main2(xb, wT, m0, n0, lane, w, smem, acc);

  // ---- epilogue: restage C tile (bf16, bias added) into LDS, then full-line stores ----
  unsigned short* Ct = (unsigned short*)smem;  // 128x128 bf16 = 32 KB
  float bsv[4];
#pragma unroll
  for (int ct = 0; ct < 4; ++ct) bsv[ct] = bias[n0 + (w >> 1) * 64 + ct * 16 + nl];
  bool isV = (n0 >= 1024);
  if (!isV) {
#pragma unroll
    for (int mt = 0; mt < 4; ++mt)
#pragma unroll
      for (int ct = 0; ct < 4; ++ct)
#pragma unroll
        for (int r = 0; r < 4; ++r) {
          int m = (w & 1) * 64 + mt * 16 + 4 * g + r;
          int n = (w >> 1) * 64 + ct * 16 + nl;
          Ct[m * 128 + (n ^ (g << 4))] = f2b(acc[mt][ct][r] + bsv[ct]);
        }
  } else {
#pragma unroll
    for (int mt = 0; mt < 4; ++mt)
#pragma unroll
      for (int ct = 0; ct < 4; ++ct) {
        int n = (w >> 1) * 64 + ct * 16 + nl;
        int mchunk = (w & 1) * 16 + mt * 4 + g;
        ushort4v pk;
#pragma unroll
        for (int r = 0; r < 4; ++r) pk[r] = f2b(acc[mt][ct][r] + bsv[ct]);
        *(ushort4v*)(Ct + n * 128 + ((mchunk ^ (n & 15)) << 2)) = pk;
      }
  }
  __syncthreads();
  int tid = threadIdx.x;
  if (!isV) {
    unsigned short* dst0 = (n0 >= 512) ? kb : qb;
#pragma unroll
    for (int i2 = 0; i2 < 8; ++i2) {
      int cid = i2 * 256 + tid;
      int row = cid >> 4, c = cid & 15;
      int gg = (row >> 2) & 3;
      short8 vv = *(const short8*)(Ct + row * 128 + ((c ^ (gg << 1)) << 3));
      int m = m0 + row, b = m >> 12, s = m & 4095;
      int ng = n0 + c * 8, h = (ng >> 6) & 7, d0 = ng & 63;
      *(short8*)(dst0 + ((size_t)(b * 8 + h) * Sc + s) * HDc + d0) = vv;
    }
  } else {
#pragma unroll
    for (int i2 = 0; i2 < 8; ++i2) {
      int cid = i2 * 256 + tid;
      int n = cid & 127, m8i = cid >> 7;
      int cpair = (m8i * 2) ^ (n & 14);
      short8 vv = *(const short8*)(Ct + n * 128 + (cpair << 2));
      if (n & 1) vv = __builtin_shufflevector(vv, vv, 4, 5, 6, 7, 0, 1, 2, 3);
      int ng = n0 + n, h = (ng >> 6) & 7, d = ng & 63;
      int m = m0 + m8i * 8, b = m >> 12, s = m & 4095;
      *(short8*)(vb + ((size_t)(b * 8 + h) * HDc + d) * Sc + s) = vv;  // V^T
    }
  }
}

// ---------------- banded attention (round-7 proven) ----------------
__global__ void k_attn(const unsigned short* __restrict__ qb,
                       const unsigned short* __restrict__ kb,
                       const unsigned short* __restrict__ vb,
                       unsigned short* __restrict__ attnb) {
  __shared__ __align__(16) char smem[40960];
  unsigned short* Qt = (unsigned short*)smem;
  unsigned short* Kt = (unsigned short*)(smem + 8192);
  unsigned short* Vt = (unsigned short*)(smem + 24576);
  unsigned short* Pt = (unsigned short*)smem;
  int bid = blockIdx.x;                        // 2048 = 8 * 4 * 64
  int x = bid & 7, i = bid >> 3;
  int bh = x * 4 + (i >> 6), qt = i & 63;
  int q0 = qt * 64;
  int tid = threadIdx.x;
  int lane = tid & 63, w = tid >> 6, g = lane >> 4;

  const unsigned short* qsrc = qb + ((long)bh * Sc + q0) * HDc;
#pragma unroll
  for (int i2 = 0; i2 < 2; ++i2) {
    int wc = i2 * 4 + w;
    int cid = wc * 64 + lane, row = cid >> 3, sl = cid & 7;
    gll16(qsrc + row * 64 + (sl ^ (row & 7)) * 8, (char*)Qt + wc * 1024);
  }
  const unsigned short* ksrc = kb + ((long)bh * Sc + q0 - HALFW) * HDc;
#pragma unroll
  for (int i2 = 0; i2 < 4; ++i2) {
    int wc = i2 * 4 + w;
    int cid = wc * 64 + lane, row = cid >> 3, sl = cid & 7;
    gll16(ksrc + row * 64 + (sl ^ (row & 7)) * 8, (char*)Kt + wc * 1024);
  }
  const unsigned short* vsrc = vb + (long)bh * HDc * Sc + (q0 - HALFW);
#pragma unroll
  for (int i2 = 0; i2 < 4; ++i2) {
    int wc = i2 * 4 + w;
    int cid = wc * 64 + lane, row = cid >> 4, sl = cid & 15;
    gll16(vsrc + (long)row * Sc + (sl ^ (row & 15)) * 8, (char*)Vt + wc * 1024);
  }
  __syncthreads();

  f32x4 sc[8];
#pragma unroll
  for (int ct = 0; ct < 8; ++ct) sc[ct] = f32x4{0.f, 0.f, 0.f, 0.f};
#pragma unroll
  for (int ksub = 0; ksub < 2; ++ksub) {
    int arow = w * 16 + (lane & 15);
    int aslot = ((ksub << 2) + g) ^ (arow & 7);
    short8 af = *(const short8*)(Qt + arow * 64 + aslot * 8);
#pragma unroll
    for (int ct = 0; ct < 8; ++ct) {
      int brow = ct * 16 + (lane & 15);
      int bslot = ((ksub << 2) + g) ^ (brow & 7);
      short8 bf = *(const short8*)(Kt + brow * 64 + bslot * 8);
      sc[ct] = __builtin_amdgcn_mfma_f32_16x16x32_bf16(af, bf, sc[ct], 0, 0, 0);
    }
  }
  float rsum[4] = {0.f, 0.f, 0.f, 0.f};
#pragma unroll
  for (int ct = 0; ct < 8; ++ct) {
    int keyl = ct * 16 + (lane & 15);
    int keyg = q0 - HALFW + keyl;
#pragma unroll
    for (int r = 0; r < 4; ++r) {
      int q = q0 + w * 16 + 4 * g + r;
      int dlt = keyg - q;
      bool valid = (dlt >= -HALFW) && (dlt <= HALFW) && (keyg >= 0) && (keyg < Sc);
      float pv = valid ? __expf(sc[ct][r] * 0.125f) : 0.f;
      sc[ct][r] = pv;
      rsum[r] += pv;
    }
  }
#pragma unroll
  for (int r = 0; r < 4; ++r) {
    float v = rsum[r];
    v += __shfl_xor(v, 1); v += __shfl_xor(v, 2); v += __shfl_xor(v, 4); v += __shfl_xor(v, 8);
    rsum[r] = 1.0f / v;
  }
  __syncthreads();
#pragma unroll
  for (int ct = 0; ct < 8; ++ct) {
    int keyl = ct * 16 + (lane & 15);
#pragma unroll
    for (int r = 0; r < 4; ++r) {
      int prow = w * 16 + 4 * g + r;
      int sp = (keyl >> 3) ^ (prow & 15);
      Pt[prow * 128 + sp * 8 + (keyl & 7)] = f2b(sc[ct][r]);
    }
  }
  __syncthreads();
  f32x4 o[4];
#pragma unroll
  for (int i2 = 0; i2 < 4; ++i2) o[i2] = f32x4{0.f, 0.f, 0.f, 0.f};
#pragma unroll
  for (int ks = 0; ks < 4; ++ks) {
    int arow = w * 16 + (lane & 15);
    int aslot = ((ks << 2) + g) ^ (arow & 15);
    short8 af = *(const short8*)(Pt + arow * 128 + aslot * 8);
#pragma unroll
    for (int ct2 = 0; ct2 < 4; ++ct2) {
      int vrow = ct2 * 16 + (lane & 15);
      int vslot = ((ks << 2) + g) ^ (vrow & 15);
      short8 bf = *(const short8*)(Vt + vrow * 128 + vslot * 8);
      o[ct2] = __builtin_amdgcn_mfma_f32_16x16x32_bf16(af, bf, o[ct2], 0, 0, 0);
    }
  }
  int h = bh & 7, b = bh >> 3;
#pragma unroll
  for (int ct2 = 0; ct2 < 4; ++ct2) {
    int d = ct2 * 16 + (lane & 15);
    int col = h * 64 + d;
    int slot = col >> 3;
#pragma unroll
    for (int r = 0; r < 4; ++r) {
      int q = q0 + w * 16 + 4 * g + r;
      int sp = (slot & ~7) | ((slot & 7) ^ (q & 7));
      attnb[((size_t)b * Sc + q) * DIMc + sp * 8 + (col & 7)] = f2b(o[ct2][r] * rsum[r]);
    }
  }
}

// ---------------- GEMM2: out = attn @ W_proj + b (round-7 proven) ----------------
__global__ void k_gemm_proj(const unsigned short* __restrict__ ab,
                            const unsigned short* __restrict__ wT,
                            const float* __restrict__ bias,
                            float* __restrict__ out) {
  __shared__ __align__(16) char smem[65536];
  int bid = blockIdx.x;                        // 512 = 8 XCD * 16 bm * 4 bn
  int x = bid & 7, i = bid >> 3;
  int bm = x * 16 + (i >> 2), bn = i & 3;
  int m0 = bm * 128, n0 = bn * 128;
  int lane = threadIdx.x & 63, w = threadIdx.x >> 6, g = lane >> 4;
  f32x4 acc[4][4];
#pragma unroll
  for (int i2 = 0; i2 < 4; ++i2)
#pragma unroll
    for (int j = 0; j < 4; ++j) acc[i2][j] = f32x4{0.f, 0.f, 0.f, 0.f};
  gemm_main2(ab, wT, m0, n0, lane, w, smem, acc);
#pragma unroll
  for (int ct = 0; ct < 4; ++ct) {
    int n = n0 + (w >> 1) * 64 + ct * 16 + (lane & 15);
    float bs = bias[n];
#pragma unroll
    for (int mt = 0; mt < 4; ++mt) {
#pragma unroll
      for (int r = 0; r < 4; ++r) {
        int m = m0 + (w & 1) * 64 + mt * 16 + 4 * g + r;
        out[(size_t)m * DIMc + n] = acc[mt][ct][r] + bs;
      }
    }
  }
}

extern "C" void kernel_launch(void* const* d_in, const int* in_sizes, int n_in,
                              void* d_out, int out_size, void* d_ws, size_t ws_size,
                              hipStream_t stream) {
  const float* x     = (const float*)d_in[0];
  const float* Wqkv  = (const float*)d_in[1];
  const float* bqkv  = (const float*)d_in[2];
  const float* Wproj = (const float*)d_in[3];
  const float* bproj = (const float*)d_in[4];
  float* out = (float*)d_out;

  char* ws = (char*)d_ws;
  const size_t SZ_QKV = (size_t)32 * Sc * HDc * 2;   // 16,777,216 each
  const size_t SZ_ATT = (size_t)Mc * DIMc * 2;       // 16,777,216
  size_t off = 0;
  unsigned short* qb    = (unsigned short*)(ws + off); off += SZ_QKV;
  unsigned short* kb    = (unsigned short*)(ws + off); off += SZ_QKV;
  unsigned short* vb    = (unsigned short*)(ws + off); off += SZ_QKV;
  unsigned short* attnb = (unsigned short*)(ws + off); off += SZ_ATT;
  unsigned short* xb    = (unsigned short*)(ws + off); off += SZ_ATT;
  unsigned short* wqkvT = (unsigned short*)(ws + off); off += (size_t)N1c * Kc * 2;
  unsigned short* wprjT = (unsigned short*)(ws + off); off += (size_t)DIMc * Kc * 2;
  if (ws_size < off) return;  // insufficient scratch; fail visibly

  k_convert_all<<<dim3(4608), dim3(256), 0, stream>>>(x, xb, Wqkv, wqkvT, Wproj, wprjT);
  k_gemm_qkv   <<<dim3(1536), dim3(256), 0, stream>>>(xb, wqkvT, bqkv, qb, kb, vb);
  k_attn       <<<dim3(2048), dim3(256), 0, stream>>>(qb, kb, vb, attnb);
  k_gemm_proj  <<<dim3(512),  dim3(256), 0, stream>>>(attnb, wprjT, bproj, out);
}